// Round 4
// baseline (521.434 us; speedup 1.0000x reference)
//
#include <hip/hip_runtime.h>
#include <hip/hip_bf16.h>
#include <math.h>

// Problem constants
#define CDIM 256
#define HW   1024          // 32*32
#define NVEC 32768         // B*H*W
#define NE   1024
#define ZSIZE 8388608      // 32*256*32*32
#define MARGIN 0.3f        // bf16-score top2 margin below which we rescore exactly (~8 sigma)

// Output layout (floats): [loss(1)][z_q(ZSIZE)][perp(1)][idx(NVEC)][z_q1(ZSIZE)]
#define OUT_LOSS 0
#define OUT_ZQ   1
#define OUT_PERP 8388609
#define OUT_IDX  8388610
#define OUT_ZQ1  8421378

// Workspace layout (bytes), total ~20.7 MB
#define WS_LOSS   0         // double
#define WS_RCNT   64        // int rescue count
#define WS_HIST   128       // 1024 ints  -> 4224
#define WS_ENORM  4224      // 1024 floats -> 8320
#define WS_IDX    8448      // 32768 ints -> 139520
#define WS_RLIST  139520    // 32768 ints -> 270592
#define WS_S1     270592    // 8*32768 floats -> 1319168
#define WS_S2     1319168   // -> 2367744
#define WS_J1     2367744   // 8*32768 ints -> 3416320
#define WS_EB     3416320   // 1024*256 bf16 -> 3940608
#define WS_ZB     3940608   // 32768*256 bf16 -> 20717824

typedef __attribute__((ext_vector_type(8))) short short8;
typedef __attribute__((ext_vector_type(4))) float f32x4;
typedef __attribute__((ext_vector_type(8))) unsigned short ushort8v;

__device__ __forceinline__ unsigned short bf16_rne(float x) {
    union { float f; unsigned u; } v; v.f = x;
    unsigned r = v.u + 0x7FFFu + ((v.u >> 16) & 1u);
    return (unsigned short)(r >> 16);
}

// ---------------- prep emb: bf16 convert + exact fp32 norms ----------------
__global__ __launch_bounds__(256) void vq_prep_e(const float* __restrict__ emb,
                                                 unsigned short* __restrict__ eb,
                                                 float* __restrict__ enorm) {
    int code = blockIdx.x * 4 + (threadIdx.x >> 6);
    int lane = threadIdx.x & 63;
    float4 v = *(const float4*)(emb + (size_t)code * CDIM + lane * 4);
    float s = v.x * v.x + v.y * v.y + v.z * v.z + v.w * v.w;
    for (int off = 32; off; off >>= 1) s += __shfl_down(s, off, 64);
    if (lane == 0) enorm[code] = s;
    ushort4 u = { bf16_rne(v.x), bf16_rne(v.y), bf16_rne(v.z), bf16_rne(v.w) };
    *(ushort4*)(eb + (size_t)code * CDIM + lane * 4) = u;
}

// ---------------- prep z: transpose [b][k][hw] -> zb[n][k] bf16 ----------------
__global__ __launch_bounds__(256) void vq_prep_z(const float* __restrict__ z,
                                                 unsigned short* __restrict__ zb) {
    __shared__ unsigned short tile[64 * 264];   // 64 hw x 256 k, pad 8
    const int tid = threadIdx.x, w = tid >> 6, L = tid & 63;
    const int b = blockIdx.x >> 4, hw0 = (blockIdx.x & 15) << 6;
    const float* zp = z + (size_t)b * (CDIM * HW) + hw0;

    for (int i = 0; i < 16; ++i) {
        int kq = i * 4 + w;          // 0..63
        int k = kq * 4;
        float f0 = zp[(size_t)(k + 0) * HW + L];
        float f1 = zp[(size_t)(k + 1) * HW + L];
        float f2 = zp[(size_t)(k + 2) * HW + L];
        float f3 = zp[(size_t)(k + 3) * HW + L];
        ushort4 u = { bf16_rne(f0), bf16_rne(f1), bf16_rne(f2), bf16_rne(f3) };
        *(ushort4*)&tile[L * 264 + k] = u;
    }
    __syncthreads();
    // write out: 32 lanes cover one 512B row; 2 rows per inst
#pragma unroll
    for (int it = 0; it < 8; ++it) {
        int row = it * 8 + (tid >> 5);
        int kc = (tid & 31) * 8;
        ushort8v v = *(ushort8v*)&tile[row * 264 + kc];
        *(ushort8v*)(zb + (size_t)(b * 1024 + hw0 + row) * CDIM + kc) = v;
    }
}

// ---------------- bf16 MFMA score GEMM + per-split top-2 argmax ----------------
// score(n,j) = z_n.e_j - 0.5||e_j||^2. Block: 128 n-rows x 128-code split.
// No LDS: A and B frags loaded straight from global in HW fragment layout
// (each wave-load consumes 16 full 64B lines; eb is L2-resident).
__global__ __launch_bounds__(256) void vq_mfma(
    const unsigned short* __restrict__ zb, const unsigned short* __restrict__ eb,
    const float* __restrict__ enorm,
    float* __restrict__ s1_ws, float* __restrict__ s2_ws, int* __restrict__ j1_ws)
{
    const int tid = threadIdx.x;
    const int w = tid >> 6, L = tid & 63;
    const int l15 = L & 15, q = L >> 4;
    const int mtile = blockIdx.x & 255, js = blockIdx.x >> 8;
    const int n0 = mtile << 7, j0 = js << 7;
    const unsigned short* a0 = zb + (size_t)(n0 + w * 32 + l15) * CDIM + q * 8;
    const unsigned short* b0 = eb + (size_t)(j0 + l15) * CDIM + q * 8;

    f32x4 acc[2][8] = {};
#pragma unroll
    for (int k0 = 0; k0 < 256; k0 += 32) {
        short8 A0 = *(const short8*)(a0 + k0);
        short8 A1 = *(const short8*)(a0 + 16 * CDIM + k0);
#pragma unroll
        for (int jf = 0; jf < 8; ++jf) {
            short8 B = *(const short8*)(b0 + jf * 16 * CDIM + k0);
            acc[0][jf] = __builtin_amdgcn_mfma_f32_16x16x32_bf16(A0, B, acc[0][jf], 0, 0, 0);
            acc[1][jf] = __builtin_amdgcn_mfma_f32_16x16x32_bf16(A1, B, acc[1][jf], 0, 0, 0);
        }
    }

    float hn[8];
#pragma unroll
    for (int jf = 0; jf < 8; ++jf) hn[jf] = 0.5f * enorm[j0 + jf * 16 + l15];

    // D[m = q*4+r][j-col = l15]; per (mf,r): top-2 over jf then across 16 cols
#pragma unroll
    for (int mf = 0; mf < 2; ++mf)
#pragma unroll
        for (int r = 0; r < 4; ++r) {
            float s1 = -3.4e38f, s2 = -3.4e38f; int j1 = 0;
#pragma unroll
            for (int jf = 0; jf < 8; ++jf) {
                float s = acc[mf][jf][r] - hn[jf];
                int j = j0 + jf * 16 + l15;
                if (s > s1) { s2 = s1; s1 = s; j1 = j; }
                else if (s > s2) s2 = s;   // s==s1 -> s2=s -> margin 0 -> rescued
            }
            for (int m = 1; m < 16; m <<= 1) {
                float os1 = __shfl_xor(s1, m, 64);
                float os2 = __shfl_xor(s2, m, 64);
                int   oj1 = __shfl_xor(j1, m, 64);
                if (os1 > s1 || (os1 == s1 && oj1 < j1)) {
                    s2 = fmaxf(s1, os2); s1 = os1; j1 = oj1;
                } else {
                    s2 = fmaxf(s2, os1);
                }
            }
            if (l15 == 0) {
                int o = js * NVEC + n0 + w * 32 + mf * 16 + q * 4 + r;
                s1_ws[o] = s1; s2_ws[o] = s2; j1_ws[o] = j1;
            }
        }
}

// ---------------- merge 8 splits; flag small-margin rows for exact rescore ----
__global__ __launch_bounds__(256) void vq_merge(
    const float* __restrict__ s1_ws, const float* __restrict__ s2_ws,
    const int* __restrict__ j1_ws, int* __restrict__ idx_ws,
    int* __restrict__ rcnt, int* __restrict__ rlist)
{
    int n = blockIdx.x * 256 + threadIdx.x;
    float b1 = -3.4e38f, b2 = -3.4e38f; int bj = 0;
#pragma unroll
    for (int s = 0; s < 8; ++s) {
        float a1 = s1_ws[s * NVEC + n], a2 = s2_ws[s * NVEC + n];
        int aj = j1_ws[s * NVEC + n];
        if (a1 > b1 || (a1 == b1 && aj < bj)) { b2 = fmaxf(b1, a2); b1 = a1; bj = aj; }
        else b2 = fmaxf(b2, a1);
    }
    idx_ws[n] = bj;
    if (b1 - b2 < MARGIN) { int p = atomicAdd(rcnt, 1); rlist[p] = n; }
}

// ---------------- exact fp32 rescore of flagged rows ----------------
__global__ __launch_bounds__(256) void vq_rescue(
    const float* __restrict__ z, const float* __restrict__ emb,
    const float* __restrict__ enorm, const int* __restrict__ rcnt,
    const int* __restrict__ rlist, int* __restrict__ idx_ws)
{
    const int tid = threadIdx.x, w = tid >> 6, L = tid & 63;
    const int count = *rcnt;
    __shared__ float zrow[4][256];
    __shared__ int rn[4];
    __shared__ float rbs[4][4];
    __shared__ int rbj[4][4];

    for (int base = blockIdx.x * 4; base < count; base += 1024) {
        int nb = min(4, count - base);
        __syncthreads();
        if (w < nb) {
            int n = rlist[base + w];
            if (L == 0) rn[w] = n;
            const float* zp = z + (size_t)(n >> 10) * (CDIM * HW) + (n & 1023);
#pragma unroll
            for (int i = 0; i < 4; ++i) zrow[w][L + 64 * i] = zp[(size_t)(L + 64 * i) * HW];
        }
        __syncthreads();
        float b1[4] = { -3.4e38f, -3.4e38f, -3.4e38f, -3.4e38f };
        int bj[4] = { 0, 0, 0, 0 };
        for (int j = w; j < NE; j += 4) {
            float4 e = *(const float4*)(emb + (size_t)j * CDIM + L * 4);
            float4 z0 = *(const float4*)&zrow[0][L * 4];
            float4 z1 = *(const float4*)&zrow[1][L * 4];
            float4 z2 = *(const float4*)&zrow[2][L * 4];
            float4 z3 = *(const float4*)&zrow[3][L * 4];
            float p0 = e.x * z0.x + e.y * z0.y + e.z * z0.z + e.w * z0.w;
            float p1 = e.x * z1.x + e.y * z1.y + e.z * z1.z + e.w * z1.w;
            float p2 = e.x * z2.x + e.y * z2.y + e.z * z2.z + e.w * z2.w;
            float p3 = e.x * z3.x + e.y * z3.y + e.z * z3.z + e.w * z3.w;
            for (int m = 1; m < 64; m <<= 1) {
                p0 += __shfl_xor(p0, m, 64);
                p1 += __shfl_xor(p1, m, 64);
                p2 += __shfl_xor(p2, m, 64);
                p3 += __shfl_xor(p3, m, 64);
            }
            float hn = 0.5f * enorm[j];
            float s0 = p0 - hn, s1 = p1 - hn, s2 = p2 - hn, s3 = p3 - hn;
            if (s0 > b1[0]) { b1[0] = s0; bj[0] = j; }
            if (s1 > b1[1]) { b1[1] = s1; bj[1] = j; }
            if (s2 > b1[2]) { b1[2] = s2; bj[2] = j; }
            if (s3 > b1[3]) { b1[3] = s3; bj[3] = j; }
        }
        if (L == 0)
#pragma unroll
            for (int i = 0; i < 4; ++i) { rbs[w][i] = b1[i]; rbj[w][i] = bj[i]; }
        __syncthreads();
        if (tid < nb) {
            float bb = -3.4e38f; int bbj = 0;
            for (int w2 = 0; w2 < 4; ++w2) {
                float s = rbs[w2][tid]; int jj = rbj[w2][tid];
                if (s > bb || (s == bb && jj < bbj)) { bb = s; bbj = jj; }
            }
            idx_ws[rn[tid]] = bbj;
        }
    }
}

// ---------------- histogram + idx output (after rescue) ----------------
__global__ __launch_bounds__(256) void vq_hist(
    const int* __restrict__ idx_ws, float* __restrict__ idx_out, int* __restrict__ hist)
{
    int n = blockIdx.x * 256 + threadIdx.x;
    int j = idx_ws[n];
    idx_out[n] = (float)j;
    atomicAdd(&hist[j], 1);
}

// ---------------- gather + outputs + loss ----------------
// Block = 64 n x 128-c half; 33KB LDS -> 4 blocks/CU (16 waves) for latency hiding.
__global__ __launch_bounds__(256) void vq_gather(
    const float* __restrict__ z, const float* __restrict__ emb,
    const int* __restrict__ idx_ws, float* __restrict__ zq,
    float* __restrict__ zq1, double* __restrict__ loss_sum)
{
    __shared__ float es[64 * 129];   // stride 129: hot read (lane + c) % 32 -> 2-way free
    __shared__ int ids[64];
    __shared__ float wred[4];

    const int tid = threadIdx.x, w = tid >> 6, L = tid & 63;
    const int b = blockIdx.x >> 5;
    const int half = (blockIdx.x >> 4) & 1;
    const int hw0 = (blockIdx.x & 15) << 6;
    const int n0 = (b << 10) + hw0;
    const int c0 = half << 7;

    if (tid < 64) ids[tid] = idx_ws[n0 + tid];
    __syncthreads();

    // stage 64 emb row-halves (128 floats each); scalar LDS writes (stride-129 rows)
#pragma unroll
    for (int p = 0; p < 8; ++p) {
        int r = p * 8 + w * 2 + (L >> 5);
        int col = (L & 31) * 4;
        float4 v = *(const float4*)(emb + (size_t)ids[r] * CDIM + c0 + col);
        es[r * 129 + col + 0] = v.x;
        es[r * 129 + col + 1] = v.y;
        es[r * 129 + col + 2] = v.z;
        es[r * 129 + col + 3] = v.w;
    }
    __syncthreads();

    const size_t zbase = (size_t)b * (CDIM * HW) + hw0;
    float ls = 0.f;
    for (int cl = w; cl < 128; cl += 4) {
        int c = c0 + cl;
        size_t off = zbase + (size_t)c * HW + L;
        float zv = z[off];
        float e = es[L * 129 + cl];
        float d = e - zv;
        zq[off] = zv + d;      // match ref: zp + (z_q1 - zp)
        zq1[off] = e;
        ls += d * d;
    }

    for (int off = 32; off; off >>= 1) ls += __shfl_down(ls, off, 64);
    if (L == 0) wred[w] = ls;
    __syncthreads();
    if (tid == 0)
        atomicAdd(loss_sum, (double)(wred[0] + wred[1] + wred[2] + wred[3]));
}

// ---------------- finalize: loss scalar + perplexity ----------------
__global__ __launch_bounds__(1024) void vq_final(
    const int* __restrict__ hist, const double* __restrict__ loss_sum,
    float* __restrict__ out_loss, float* __restrict__ out_perp)
{
    int tid = threadIdx.x;
    float em = (float)hist[tid] * (1.0f / 32768.0f);
    float term = em * logf(em + 1e-10f);
    for (int off = 32; off; off >>= 1) term += __shfl_down(term, off, 64);
    __shared__ float red[16];
    int lane = tid & 63, wv = tid >> 6;
    if (lane == 0) red[wv] = term;
    __syncthreads();
    if (tid == 0) {
        float s = 0.f;
        for (int i = 0; i < 16; ++i) s += red[i];
        *out_perp = expf(-s);
        *out_loss = (float)(*loss_sum * 1.25 / 8388608.0);
    }
}

extern "C" void kernel_launch(void* const* d_in, const int* in_sizes, int n_in,
                              void* d_out, int out_size, void* d_ws, size_t ws_size,
                              hipStream_t stream) {
    const float* z   = (const float*)d_in[0];
    const float* emb = (const float*)d_in[1];
    float* out = (float*)d_out;
    char*  ws  = (char*)d_ws;

    double* loss_sum       = (double*)(ws + WS_LOSS);
    int*    rcnt           = (int*)(ws + WS_RCNT);
    int*    hist           = (int*)(ws + WS_HIST);
    float*  enorm          = (float*)(ws + WS_ENORM);
    int*    idx_ws         = (int*)(ws + WS_IDX);
    int*    rlist          = (int*)(ws + WS_RLIST);
    float*  s1_ws          = (float*)(ws + WS_S1);
    float*  s2_ws          = (float*)(ws + WS_S2);
    int*    j1_ws          = (int*)(ws + WS_J1);
    unsigned short* eb     = (unsigned short*)(ws + WS_EB);
    unsigned short* zb     = (unsigned short*)(ws + WS_ZB);

    hipMemsetAsync(d_ws, 0, 4224, stream);   // loss + rcnt + hist

    vq_prep_e<<<256, 256, 0, stream>>>(emb, eb, enorm);
    vq_prep_z<<<512, 256, 0, stream>>>(z, zb);
    vq_mfma  <<<2048, 256, 0, stream>>>(zb, eb, enorm, s1_ws, s2_ws, j1_ws);
    vq_merge <<<128, 256, 0, stream>>>(s1_ws, s2_ws, j1_ws, idx_ws, rcnt, rlist);
    vq_rescue<<<256, 256, 0, stream>>>(z, emb, enorm, rcnt, rlist, idx_ws);
    vq_hist  <<<128, 256, 0, stream>>>(idx_ws, out + OUT_IDX, hist);
    vq_gather<<<1024, 256, 0, stream>>>(z, emb, idx_ws, out + OUT_ZQ, out + OUT_ZQ1, loss_sum);
    vq_final <<<1, 1024, 0, stream>>>(hist, loss_sum, out + OUT_LOSS, out + OUT_PERP);
}

// Round 5
// 418.137 us; speedup vs baseline: 1.2470x; 1.2470x over previous
//
#include <hip/hip_runtime.h>
#include <hip/hip_bf16.h>
#include <math.h>

// Problem constants
#define CDIM 256
#define HW   1024          // 32*32
#define NVEC 32768         // B*H*W
#define NE   1024
#define ZSIZE 8388608      // 32*256*32*32
#define MARGIN 0.05f       // split-bf16 score error sigma ~1e-4 -> 500 sigma

// Output layout (floats): [loss(1)][z_q(ZSIZE)][perp(1)][idx(NVEC)][z_q1(ZSIZE)]
#define OUT_LOSS 0
#define OUT_ZQ   1
#define OUT_PERP 8388609
#define OUT_IDX  8388610
#define OUT_ZQ1  8421378

// Workspace layout (bytes), total ~38 MB
#define WS_LOSS   0
#define WS_RCNT   64
#define WS_HIST   128       // 1024 ints  -> 4224
#define WS_ENORM  4224      // 1024 floats -> 8320
#define WS_IDX    8448      // 32768 ints -> 139520
#define WS_RLIST  139520    // 32768 ints -> 270592
#define WS_S1     270592    // 8*32768 f  -> 1319168
#define WS_S2     1319168   // -> 2367744
#define WS_J1     2367744   // -> 3416320
#define WS_EBH    3416320   // 1024*256 bf16 -> 3940608
#define WS_EBL    3940608   // -> 4464896
#define WS_ZBH    4464896   // 32768*256 bf16 -> 21242112
#define WS_ZBL    21242112  // -> 38019328

typedef __attribute__((ext_vector_type(8))) short short8;
typedef __attribute__((ext_vector_type(4))) float f32x4;
typedef __attribute__((ext_vector_type(8))) unsigned short ushort8v;

__device__ __forceinline__ unsigned short bf16_rne(float x) {
    union { float f; unsigned u; } v; v.f = x;
    unsigned r = v.u + 0x7FFFu + ((v.u >> 16) & 1u);
    return (unsigned short)(r >> 16);
}
__device__ __forceinline__ float bf16_to_f(unsigned short h) {
    union { unsigned u; float f; } v; v.u = ((unsigned)h) << 16;
    return v.f;
}

// ---------------- prep emb: bf16 hi/lo split + exact fp32 norms ----------------
__global__ __launch_bounds__(256) void vq_prep_e(const float* __restrict__ emb,
                                                 unsigned short* __restrict__ ebh,
                                                 unsigned short* __restrict__ ebl,
                                                 float* __restrict__ enorm) {
    int code = blockIdx.x * 4 + (threadIdx.x >> 6);
    int lane = threadIdx.x & 63;
    float4 v = *(const float4*)(emb + (size_t)code * CDIM + lane * 4);
    float s = v.x * v.x + v.y * v.y + v.z * v.z + v.w * v.w;
    for (int off = 32; off; off >>= 1) s += __shfl_down(s, off, 64);
    if (lane == 0) enorm[code] = s;
    ushort4 hi = { bf16_rne(v.x), bf16_rne(v.y), bf16_rne(v.z), bf16_rne(v.w) };
    ushort4 lo = { bf16_rne(v.x - bf16_to_f(hi.x)), bf16_rne(v.y - bf16_to_f(hi.y)),
                   bf16_rne(v.z - bf16_to_f(hi.z)), bf16_rne(v.w - bf16_to_f(hi.w)) };
    *(ushort4*)(ebh + (size_t)code * CDIM + lane * 4) = hi;
    *(ushort4*)(ebl + (size_t)code * CDIM + lane * 4) = lo;
}

// ---------------- prep z: transpose [b][k][hw] -> zb_hi/zb_lo [n][k] bf16 -------
__global__ __launch_bounds__(256) void vq_prep_z(const float* __restrict__ z,
                                                 unsigned short* __restrict__ zbh,
                                                 unsigned short* __restrict__ zbl) {
    __shared__ unsigned short th[64 * 264];
    __shared__ unsigned short tl[64 * 264];
    const int tid = threadIdx.x, w = tid >> 6, L = tid & 63;
    const int b = blockIdx.x >> 4, hw0 = (blockIdx.x & 15) << 6;
    const float* zp = z + (size_t)b * (CDIM * HW) + hw0;

    for (int i = 0; i < 16; ++i) {
        int k = (i * 4 + w) * 4;
        float f0 = zp[(size_t)(k + 0) * HW + L];
        float f1 = zp[(size_t)(k + 1) * HW + L];
        float f2 = zp[(size_t)(k + 2) * HW + L];
        float f3 = zp[(size_t)(k + 3) * HW + L];
        ushort4 hi = { bf16_rne(f0), bf16_rne(f1), bf16_rne(f2), bf16_rne(f3) };
        ushort4 lo = { bf16_rne(f0 - bf16_to_f(hi.x)), bf16_rne(f1 - bf16_to_f(hi.y)),
                       bf16_rne(f2 - bf16_to_f(hi.z)), bf16_rne(f3 - bf16_to_f(hi.w)) };
        *(ushort4*)&th[L * 264 + k] = hi;
        *(ushort4*)&tl[L * 264 + k] = lo;
    }
    __syncthreads();
#pragma unroll
    for (int it = 0; it < 8; ++it) {
        int row = it * 8 + (tid >> 5);
        int kc = (tid & 31) * 8;
        size_t o = (size_t)(b * 1024 + hw0 + row) * CDIM + kc;
        *(ushort8v*)(zbh + o) = *(ushort8v*)&th[row * 264 + kc];
        *(ushort8v*)(zbl + o) = *(ushort8v*)&tl[row * 264 + kc];
    }
}

// ---------------- 3-term split-bf16 MFMA score GEMM + per-split top-2 ----------
// score(n,j) ~= z_n.e_j - 0.5||e_j||^2 with error sigma ~1e-4:
//   acc = Ah.Bh + Ah.Bl + Al.Bh   (Al.Bl term ~6e-5 dropped)
__global__ __launch_bounds__(256) void vq_mfma3(
    const unsigned short* __restrict__ zbh, const unsigned short* __restrict__ zbl,
    const unsigned short* __restrict__ ebh, const unsigned short* __restrict__ ebl,
    const float* __restrict__ enorm,
    float* __restrict__ s1_ws, float* __restrict__ s2_ws, int* __restrict__ j1_ws)
{
    const int tid = threadIdx.x;
    const int w = tid >> 6, L = tid & 63;
    const int l15 = L & 15, q = L >> 4;
    const int mtile = blockIdx.x & 255, js = blockIdx.x >> 8;
    const int n0 = mtile << 7, j0 = js << 7;
    const size_t arow = (size_t)(n0 + w * 32 + l15) * CDIM + q * 8;
    const size_t brow = (size_t)(j0 + l15) * CDIM + q * 8;
    const unsigned short* ah = zbh + arow;
    const unsigned short* al = zbl + arow;
    const unsigned short* bh = ebh + brow;
    const unsigned short* bl = ebl + brow;

    f32x4 acc[2][8] = {};
#pragma unroll
    for (int k0 = 0; k0 < 256; k0 += 32) {
        short8 Ah0 = *(const short8*)(ah + k0);
        short8 Ah1 = *(const short8*)(ah + 16 * CDIM + k0);
        short8 Al0 = *(const short8*)(al + k0);
        short8 Al1 = *(const short8*)(al + 16 * CDIM + k0);
#pragma unroll
        for (int jf = 0; jf < 8; ++jf) {
            short8 Bh = *(const short8*)(bh + jf * 16 * CDIM + k0);
            short8 Bl = *(const short8*)(bl + jf * 16 * CDIM + k0);
            acc[0][jf] = __builtin_amdgcn_mfma_f32_16x16x32_bf16(Ah0, Bh, acc[0][jf], 0, 0, 0);
            acc[1][jf] = __builtin_amdgcn_mfma_f32_16x16x32_bf16(Ah1, Bh, acc[1][jf], 0, 0, 0);
            acc[0][jf] = __builtin_amdgcn_mfma_f32_16x16x32_bf16(Ah0, Bl, acc[0][jf], 0, 0, 0);
            acc[1][jf] = __builtin_amdgcn_mfma_f32_16x16x32_bf16(Ah1, Bl, acc[1][jf], 0, 0, 0);
            acc[0][jf] = __builtin_amdgcn_mfma_f32_16x16x32_bf16(Al0, Bh, acc[0][jf], 0, 0, 0);
            acc[1][jf] = __builtin_amdgcn_mfma_f32_16x16x32_bf16(Al1, Bh, acc[1][jf], 0, 0, 0);
        }
    }

    float hn[8];
#pragma unroll
    for (int jf = 0; jf < 8; ++jf) hn[jf] = 0.5f * enorm[j0 + jf * 16 + l15];

    // D[m=q*4+r][col=l15]; top-2 over jf within lane, then across 16 cols
#pragma unroll
    for (int mf = 0; mf < 2; ++mf)
#pragma unroll
        for (int r = 0; r < 4; ++r) {
            float s1 = -3.4e38f, s2 = -3.4e38f; int j1 = 0;
#pragma unroll
            for (int jf = 0; jf < 8; ++jf) {
                float s = acc[mf][jf][r] - hn[jf];
                int j = j0 + jf * 16 + l15;
                if (s > s1) { s2 = s1; s1 = s; j1 = j; }
                else if (s > s2) s2 = s;   // ties -> margin 0 -> rescued
            }
            for (int m = 1; m < 16; m <<= 1) {
                float os1 = __shfl_xor(s1, m, 64);
                float os2 = __shfl_xor(s2, m, 64);
                int   oj1 = __shfl_xor(j1, m, 64);
                if (os1 > s1 || (os1 == s1 && oj1 < j1)) {
                    s2 = fmaxf(s1, os2); s1 = os1; j1 = oj1;
                } else {
                    s2 = fmaxf(s2, os1);
                }
            }
            if (l15 == 0) {
                int o = js * NVEC + n0 + w * 32 + mf * 16 + q * 4 + r;
                s1_ws[o] = s1; s2_ws[o] = s2; j1_ws[o] = j1;
            }
        }
}

// ---------------- merge 8 splits; flag small-margin rows -----------------------
__global__ __launch_bounds__(256) void vq_merge(
    const float* __restrict__ s1_ws, const float* __restrict__ s2_ws,
    const int* __restrict__ j1_ws, int* __restrict__ idx_ws,
    int* __restrict__ rcnt, int* __restrict__ rlist)
{
    int n = blockIdx.x * 256 + threadIdx.x;
    float b1 = -3.4e38f, b2 = -3.4e38f; int bj = 0;
#pragma unroll
    for (int s = 0; s < 8; ++s) {
        float a1 = s1_ws[s * NVEC + n], a2 = s2_ws[s * NVEC + n];
        int aj = j1_ws[s * NVEC + n];
        if (a1 > b1 || (a1 == b1 && aj < bj)) { b2 = fmaxf(b1, a2); b1 = a1; bj = aj; }
        else b2 = fmaxf(b2, a1);
    }
    idx_ws[n] = bj;
    if (b1 - b2 < MARGIN) { int p = atomicAdd(rcnt, 1); rlist[p] = n; }
}

// ---------------- exact fp32 rescore of flagged rows ---------------------------
// One row per block iteration; one j per THREAD (no per-j cross-lane reduce).
// Reproduces R1-R3 exact semantics: fp32 fmaf, k ascending, first-j tie-break.
__global__ __launch_bounds__(256) void vq_rescue(
    const float* __restrict__ z, const float* __restrict__ emb,
    const float* __restrict__ enorm, const int* __restrict__ rcnt,
    const int* __restrict__ rlist, int* __restrict__ idx_ws)
{
    __shared__ float zrow[256];
    __shared__ float rs[256];
    __shared__ int   rj[256];
    const int tid = threadIdx.x;
    const int count = *rcnt;

    for (int it = blockIdx.x; it < count; it += gridDim.x) {
        __syncthreads();
        int n = rlist[it];
        zrow[tid] = z[(size_t)(n >> 10) * (CDIM * HW) + (size_t)tid * HW + (n & 1023)];
        __syncthreads();

        float b1 = -3.4e38f; int bj = 0;
#pragma unroll
        for (int jj = 0; jj < 4; ++jj) {
            int j = jj * 256 + tid;
            const float* er = emb + (size_t)j * CDIM;
            float s = 0.f;
#pragma unroll 4
            for (int kc = 0; kc < 256; kc += 4) {
                float4 e = *(const float4*)(er + kc);
                s = fmaf(zrow[kc + 0], e.x, s);
                s = fmaf(zrow[kc + 1], e.y, s);
                s = fmaf(zrow[kc + 2], e.z, s);
                s = fmaf(zrow[kc + 3], e.w, s);
            }
            s -= 0.5f * enorm[j];
            if (s > b1) { b1 = s; bj = j; }   // per-thread j's ascending
        }
        rs[tid] = b1; rj[tid] = bj;
        __syncthreads();
        for (int step = 128; step >= 1; step >>= 1) {
            if (tid < step) {
                float so = rs[tid + step]; int jo = rj[tid + step];
                if (so > rs[tid] || (so == rs[tid] && jo < rj[tid])) { rs[tid] = so; rj[tid] = jo; }
            }
            __syncthreads();
        }
        if (tid == 0) idx_ws[n] = rj[0];
    }
}

// ---------------- histogram + idx output (after rescue) ------------------------
__global__ __launch_bounds__(256) void vq_hist(
    const int* __restrict__ idx_ws, float* __restrict__ idx_out, int* __restrict__ hist)
{
    int n = blockIdx.x * 256 + threadIdx.x;
    int j = idx_ws[n];
    idx_out[n] = (float)j;
    atomicAdd(&hist[j], 1);
}

// ---------------- gather + outputs + loss --------------------------------------
// Block = 32 n-rows x 128-c half; 16.6KB LDS -> 8 blocks/CU (32 waves).
__global__ __launch_bounds__(256) void vq_gather(
    const float* __restrict__ z, const float* __restrict__ emb,
    const int* __restrict__ idx_ws, float* __restrict__ zq,
    float* __restrict__ zq1, double* __restrict__ loss_sum)
{
    __shared__ float es[32 * 129];   // stride 129: hot read (row + c) % 32 -> 2-way free
    __shared__ int ids[32];
    __shared__ float wred[4];

    const int tid = threadIdx.x, w = tid >> 6, L = tid & 63;
    const int b   = blockIdx.x >> 6;
    const int half = (blockIdx.x >> 5) & 1;
    const int hw0 = (blockIdx.x & 31) << 5;
    const int n0  = (b << 10) + hw0;
    const int c0  = half << 7;

    if (tid < 32) ids[tid] = idx_ws[n0 + tid];
    __syncthreads();

    // stage 32 emb row-halves (128 floats each), coalesced 512B/row
#pragma unroll
    for (int p = 0; p < 4; ++p) {
        int u = p * 256 + tid;
        int r = u >> 5, cq = (u & 31) * 4;
        float4 v = *(const float4*)(emb + (size_t)ids[r] * CDIM + c0 + cq);
        es[r * 129 + cq + 0] = v.x;
        es[r * 129 + cq + 1] = v.y;
        es[r * 129 + cq + 2] = v.z;
        es[r * 129 + cq + 3] = v.w;
    }
    __syncthreads();

    const int row = L & 31, cp = L >> 5;
    const size_t zbase = (size_t)b * (CDIM * HW) + hw0 + row;
    float ls = 0.f;
    for (int rd = 0; rd < 16; ++rd) {
        int cl = rd * 8 + w * 2 + cp;
        size_t off = zbase + (size_t)(c0 + cl) * HW;
        float zv = z[off];
        float e  = es[row * 129 + cl];
        float d  = e - zv;
        zq[off]  = zv + d;     // match ref: zp + (z_q1 - zp)
        zq1[off] = e;
        ls += d * d;
    }

    for (int off = 32; off; off >>= 1) ls += __shfl_down(ls, off, 64);
    if (L == 0) wred[w] = ls;
    __syncthreads();
    if (tid == 0)
        atomicAdd(loss_sum, (double)(wred[0] + wred[1] + wred[2] + wred[3]));
}

// ---------------- finalize: loss scalar + perplexity ---------------------------
__global__ __launch_bounds__(1024) void vq_final(
    const int* __restrict__ hist, const double* __restrict__ loss_sum,
    float* __restrict__ out_loss, float* __restrict__ out_perp)
{
    int tid = threadIdx.x;
    float em = (float)hist[tid] * (1.0f / 32768.0f);
    float term = em * logf(em + 1e-10f);
    for (int off = 32; off; off >>= 1) term += __shfl_down(term, off, 64);
    __shared__ float red[16];
    int lane = tid & 63, wv = tid >> 6;
    if (lane == 0) red[wv] = term;
    __syncthreads();
    if (tid == 0) {
        float s = 0.f;
        for (int i = 0; i < 16; ++i) s += red[i];
        *out_perp = expf(-s);
        *out_loss = (float)(*loss_sum * 1.25 / 8388608.0);
    }
}

extern "C" void kernel_launch(void* const* d_in, const int* in_sizes, int n_in,
                              void* d_out, int out_size, void* d_ws, size_t ws_size,
                              hipStream_t stream) {
    const float* z   = (const float*)d_in[0];
    const float* emb = (const float*)d_in[1];
    float* out = (float*)d_out;
    char*  ws  = (char*)d_ws;

    double* loss_sum   = (double*)(ws + WS_LOSS);
    int*    rcnt       = (int*)(ws + WS_RCNT);
    int*    hist       = (int*)(ws + WS_HIST);
    float*  enorm      = (float*)(ws + WS_ENORM);
    int*    idx_ws     = (int*)(ws + WS_IDX);
    int*    rlist      = (int*)(ws + WS_RLIST);
    float*  s1_ws      = (float*)(ws + WS_S1);
    float*  s2_ws      = (float*)(ws + WS_S2);
    int*    j1_ws      = (int*)(ws + WS_J1);
    unsigned short* ebh = (unsigned short*)(ws + WS_EBH);
    unsigned short* ebl = (unsigned short*)(ws + WS_EBL);
    unsigned short* zbh = (unsigned short*)(ws + WS_ZBH);
    unsigned short* zbl = (unsigned short*)(ws + WS_ZBL);

    hipMemsetAsync(d_ws, 0, 4224, stream);   // loss + rcnt + hist

    vq_prep_e<<<256, 256, 0, stream>>>(emb, ebh, ebl, enorm);
    vq_prep_z<<<512, 256, 0, stream>>>(z, zbh, zbl);
    vq_mfma3 <<<2048, 256, 0, stream>>>(zbh, zbl, ebh, ebl, enorm, s1_ws, s2_ws, j1_ws);
    vq_merge <<<128, 256, 0, stream>>>(s1_ws, s2_ws, j1_ws, idx_ws, rcnt, rlist);
    vq_rescue<<<128, 256, 0, stream>>>(z, emb, enorm, rcnt, rlist, idx_ws);
    vq_hist  <<<128, 256, 0, stream>>>(idx_ws, out + OUT_IDX, hist);
    vq_gather<<<2048, 256, 0, stream>>>(z, emb, idx_ws, out + OUT_ZQ, out + OUT_ZQ1, loss_sum);
    vq_final <<<1, 1024, 0, stream>>>(hist, loss_sum, out + OUT_LOSS, out + OUT_PERP);
}

// Round 6
// 302.492 us; speedup vs baseline: 1.7238x; 1.3823x over previous
//
#include <hip/hip_runtime.h>
#include <hip/hip_bf16.h>
#include <math.h>

// Problem constants
#define CDIM 256
#define HW   1024          // 32*32
#define NVEC 32768         // B*H*W
#define NE   1024
#define ZSIZE 8388608      // 32*256*32*32
#define NSPLIT 2           // j-splits (512 codes each)
#define MARGIN 0.05f       // 3-term split-bf16 score error sigma ~1e-4 -> 500 sigma

// Output layout (floats): [loss(1)][z_q(ZSIZE)][perp(1)][idx(NVEC)][z_q1(ZSIZE)]
#define OUT_LOSS 0
#define OUT_ZQ   1
#define OUT_PERP 8388609
#define OUT_IDX  8388610
#define OUT_ZQ1  8421378

// Workspace layout (bytes)
#define WS_LOSS   0
#define WS_RCNT   64
#define WS_HIST   128       // 1024 ints  -> 4224
#define WS_ENORM  4224      // 1024 floats -> 8320
#define WS_IDX    8448      // 32768 ints -> 139520
#define WS_RLIST  139520    // 32768 ints -> 270592
#define WS_S1     270592    // 2*32768 f  -> 532736
#define WS_S2     532736    // -> 794880
#define WS_J1     794880    // -> 1057024
#define WS_EBH    1057024   // 1024*256 bf16 -> 1581312
#define WS_EBL    1581312   // -> 2105600
#define WS_ZBH    2105600   // 32768*256 bf16 -> 18882816
#define WS_ZBL    18882816  // -> 35660032

typedef __attribute__((ext_vector_type(8))) short short8;
typedef __attribute__((ext_vector_type(4))) float f32x4;
typedef __attribute__((ext_vector_type(8))) unsigned short ushort8v;

__device__ __forceinline__ unsigned short bf16_rne(float x) {
    union { float f; unsigned u; } v; v.f = x;
    unsigned r = v.u + 0x7FFFu + ((v.u >> 16) & 1u);
    return (unsigned short)(r >> 16);
}
__device__ __forceinline__ float bf16_to_f(unsigned short h) {
    union { unsigned u; float f; } v; v.u = ((unsigned)h) << 16;
    return v.f;
}
// CK-style block_sync_lds: drains LDS ops + barrier, leaves global loads (vmcnt) in flight.
__device__ __forceinline__ void lds_barrier() {
    asm volatile("s_waitcnt lgkmcnt(0)\n\ts_barrier" ::: "memory");
}

// ---------------- fused prep: z transpose+split (blocks 0..511), emb split+norm (512..527)
__global__ __launch_bounds__(256) void vq_prep(
    const float* __restrict__ z, const float* __restrict__ emb,
    unsigned short* __restrict__ zbh, unsigned short* __restrict__ zbl,
    unsigned short* __restrict__ ebh, unsigned short* __restrict__ ebl,
    float* __restrict__ enorm)
{
    const int tid = threadIdx.x, w = tid >> 6, L = tid & 63;
    if (blockIdx.x < 512) {
        __shared__ unsigned short th[64 * 264];
        __shared__ unsigned short tl[64 * 264];
        const int b = blockIdx.x >> 4, hw0 = (blockIdx.x & 15) << 6;
        const float* zp = z + (size_t)b * (CDIM * HW) + hw0;
        for (int i = 0; i < 16; ++i) {
            int k = (i * 4 + w) * 4;
            float f0 = zp[(size_t)(k + 0) * HW + L];
            float f1 = zp[(size_t)(k + 1) * HW + L];
            float f2 = zp[(size_t)(k + 2) * HW + L];
            float f3 = zp[(size_t)(k + 3) * HW + L];
            ushort4 hi = { bf16_rne(f0), bf16_rne(f1), bf16_rne(f2), bf16_rne(f3) };
            ushort4 lo = { bf16_rne(f0 - bf16_to_f(hi.x)), bf16_rne(f1 - bf16_to_f(hi.y)),
                           bf16_rne(f2 - bf16_to_f(hi.z)), bf16_rne(f3 - bf16_to_f(hi.w)) };
            *(ushort4*)&th[L * 264 + k] = hi;
            *(ushort4*)&tl[L * 264 + k] = lo;
        }
        __syncthreads();
#pragma unroll
        for (int it = 0; it < 8; ++it) {
            int row = it * 8 + (tid >> 5);
            int kc = (tid & 31) * 8;
            size_t o = (size_t)(b * 1024 + hw0 + row) * CDIM + kc;
            *(ushort8v*)(zbh + o) = *(ushort8v*)&th[row * 264 + kc];
            *(ushort8v*)(zbl + o) = *(ushort8v*)&tl[row * 264 + kc];
        }
    } else {
        const int cb = (int)(blockIdx.x - 512) * 64;
        for (int p = 0; p < 16; ++p) {
            int code = cb + p * 4 + w;
            float4 v = *(const float4*)(emb + (size_t)code * CDIM + L * 4);
            float s = v.x * v.x + v.y * v.y + v.z * v.z + v.w * v.w;
            for (int off = 32; off; off >>= 1) s += __shfl_down(s, off, 64);
            if (L == 0) enorm[code] = s;
            ushort4 hi = { bf16_rne(v.x), bf16_rne(v.y), bf16_rne(v.z), bf16_rne(v.w) };
            ushort4 lo = { bf16_rne(v.x - bf16_to_f(hi.x)), bf16_rne(v.y - bf16_to_f(hi.y)),
                           bf16_rne(v.z - bf16_to_f(hi.z)), bf16_rne(v.w - bf16_to_f(hi.w)) };
            *(ushort4*)(ebh + (size_t)code * CDIM + L * 4) = hi;
            *(ushort4*)(ebl + (size_t)code * CDIM + L * 4) = lo;
        }
    }
}

// ---------------- 3-term split-bf16 MFMA GEMM, LDS-staged, j-loop inside ----------
// Block: 128 n-rows x 512-j split; 4 waves (wave w = rows n0+w*32..+31).
// AH in regs; AL in LDS fragment-order (64KB, staged once); B per (j0,kk) tile in
// LDS fragment-order (16KB, single buffer, reg-prefetched, manual lds_barrier so
// prefetch global loads stay in flight across barriers).
__global__ __launch_bounds__(256, 2) void vq_mfma3(
    const unsigned short* __restrict__ zbh, const unsigned short* __restrict__ zbl,
    const unsigned short* __restrict__ ebh, const unsigned short* __restrict__ ebl,
    const float* __restrict__ enorm,
    float* __restrict__ s1_ws, float* __restrict__ s2_ws, int* __restrict__ j1_ws)
{
    __shared__ short albuf[32768];   // 64KB: AL frags, seg(w,mf,kk)=w*16+mf*8+kk, 512 shorts/seg
    __shared__ short bbuf[8192];     // 16KB: B frags, hi: seg=jf, lo: seg=8+jf

    const int tid = threadIdx.x, w = tid >> 6, L = tid & 63;
    const int l15 = L & 15, q = L >> 4;
    const int r16 = tid & 15, ch = (tid >> 4) & 3;
    const int mtile = blockIdx.x & 255, js = blockIdx.x >> 8;
    const int n0 = mtile << 7;
    const int jsbase = js << 9;

    // stage AL (fragment order): 16 rounds x (global b128 -> ds_write_b128)
#pragma unroll
    for (int ro = 0; ro < 16; ++ro) {
        const int w2 = ro >> 2, mf = (ro >> 1) & 1, kk = (ro & 1) * 4 + 0; // decode below
        // seg = ro*4 + w ; w2=seg>>4, mf=(seg>>3)&1, kk=seg&7
        const int seg = ro * 4 + w;
        const int sw2 = seg >> 4, smf = (seg >> 3) & 1, skk = seg & 7;
        short8 v = *(const short8*)(zbl + (size_t)(n0 + sw2 * 32 + smf * 16 + r16) * CDIM + skk * 32 + ch * 8);
        *(short8*)(albuf + seg * 512 + L * 8) = v;
        (void)w2; (void)mf; (void)kk;
    }
    // AH into regs (16 b128 per lane)
    short8 AH[2][8];
#pragma unroll
    for (int mf = 0; mf < 2; ++mf)
#pragma unroll
        for (int kk = 0; kk < 8; ++kk)
            AH[mf][kk] = *(const short8*)(zbh + (size_t)(n0 + w * 32 + mf * 16 + l15) * CDIM + kk * 32 + q * 8);
    __syncthreads();

    float s1[2][4], s2[2][4]; int j1[2][4];
#pragma unroll
    for (int mf = 0; mf < 2; ++mf)
#pragma unroll
        for (int r = 0; r < 4; ++r) { s1[mf][r] = -3.4e38f; s2[mf][r] = -3.4e38f; j1[mf][r] = 0; }

    for (int j0i = 0; j0i < 4; ++j0i) {
        const int j0 = jsbase + j0i * 128;
        f32x4 acc[2][8] = {};
        // prefetch B tile kk=0: seg=ro*4+w -> h=ro>>1, jf=(ro&1)*4+w
        short8 st[4];
#pragma unroll
        for (int ro = 0; ro < 4; ++ro) {
            const unsigned short* src = (ro >= 2) ? ebl : ebh;
            const int jf = (ro & 1) * 4 + w;
            st[ro] = *(const short8*)(src + (size_t)(j0 + jf * 16 + r16) * CDIM + ch * 8);
        }
#pragma unroll
        for (int kk = 0; kk < 8; ++kk) {
            lds_barrier();                 // readers of previous tile done
#pragma unroll
            for (int ro = 0; ro < 4; ++ro)
                *(short8*)(bbuf + (ro * 4 + w) * 512 + L * 8) = st[ro];
            if (kk < 7) {
                const int k0n = (kk + 1) * 32;
#pragma unroll
                for (int ro = 0; ro < 4; ++ro) {
                    const unsigned short* src = (ro >= 2) ? ebl : ebh;
                    const int jf = (ro & 1) * 4 + w;
                    st[ro] = *(const short8*)(src + (size_t)(j0 + jf * 16 + r16) * CDIM + k0n + ch * 8);
                }
            }
            lds_barrier();                 // writes visible; prefetch stays in flight
            short8 AL0 = *(const short8*)(albuf + (w * 16 + kk) * 512 + L * 8);
            short8 AL1 = *(const short8*)(albuf + (w * 16 + 8 + kk) * 512 + L * 8);
#pragma unroll
            for (int jf = 0; jf < 8; ++jf) {
                short8 Bh = *(const short8*)(bbuf + jf * 512 + L * 8);
                short8 Bl = *(const short8*)(bbuf + (8 + jf) * 512 + L * 8);
                acc[0][jf] = __builtin_amdgcn_mfma_f32_16x16x32_bf16(AH[0][kk], Bh, acc[0][jf], 0, 0, 0);
                acc[1][jf] = __builtin_amdgcn_mfma_f32_16x16x32_bf16(AH[1][kk], Bh, acc[1][jf], 0, 0, 0);
                acc[0][jf] = __builtin_amdgcn_mfma_f32_16x16x32_bf16(AH[0][kk], Bl, acc[0][jf], 0, 0, 0);
                acc[1][jf] = __builtin_amdgcn_mfma_f32_16x16x32_bf16(AH[1][kk], Bl, acc[1][jf], 0, 0, 0);
                acc[0][jf] = __builtin_amdgcn_mfma_f32_16x16x32_bf16(AL0, Bh, acc[0][jf], 0, 0, 0);
                acc[1][jf] = __builtin_amdgcn_mfma_f32_16x16x32_bf16(AL1, Bh, acc[1][jf], 0, 0, 0);
            }
        }
        // fold this j0's 128 cols into running per-lane top-2 (j ascending)
#pragma unroll
        for (int jf = 0; jf < 8; ++jf) {
            const int j = j0 + jf * 16 + l15;
            const float hn = 0.5f * enorm[j];
#pragma unroll
            for (int mf = 0; mf < 2; ++mf)
#pragma unroll
                for (int r = 0; r < 4; ++r) {
                    float s = acc[mf][jf][r] - hn;
                    if (s > s1[mf][r]) { s2[mf][r] = s1[mf][r]; s1[mf][r] = s; j1[mf][r] = j; }
                    else if (s > s2[mf][r]) s2[mf][r] = s;
                }
        }
    }

    // cross-lane top-2 merge over the 16 l15 lanes, then write per-split results
#pragma unroll
    for (int mf = 0; mf < 2; ++mf)
#pragma unroll
        for (int r = 0; r < 4; ++r) {
            float a1 = s1[mf][r], a2 = s2[mf][r]; int aj = j1[mf][r];
            for (int m = 1; m < 16; m <<= 1) {
                float o1 = __shfl_xor(a1, m, 64);
                float o2 = __shfl_xor(a2, m, 64);
                int   oj = __shfl_xor(aj, m, 64);
                if (o1 > a1 || (o1 == a1 && oj < aj)) { a2 = fmaxf(a1, o2); a1 = o1; aj = oj; }
                else a2 = fmaxf(a2, o1);
            }
            if (l15 == 0) {
                int o = js * NVEC + n0 + w * 32 + mf * 16 + q * 4 + r;
                s1_ws[o] = a1; s2_ws[o] = a2; j1_ws[o] = aj;
            }
        }
}

// ---------------- merge 2 splits; hist+idx_out for confident rows; flag rest ----
__global__ __launch_bounds__(256) void vq_merge(
    const float* __restrict__ s1_ws, const float* __restrict__ s2_ws,
    const int* __restrict__ j1_ws, int* __restrict__ idx_ws,
    float* __restrict__ idx_out, int* __restrict__ hist,
    int* __restrict__ rcnt, int* __restrict__ rlist)
{
    int n = blockIdx.x * 256 + threadIdx.x;
    float b1 = -3.4e38f, b2 = -3.4e38f; int bj = 0;
#pragma unroll
    for (int s = 0; s < NSPLIT; ++s) {
        float a1 = s1_ws[s * NVEC + n], a2 = s2_ws[s * NVEC + n];
        int aj = j1_ws[s * NVEC + n];
        if (a1 > b1 || (a1 == b1 && aj < bj)) { b2 = fmaxf(b1, a2); b1 = a1; bj = aj; }
        else b2 = fmaxf(b2, a1);
    }
    idx_ws[n] = bj;
    if (b1 - b2 < MARGIN) {
        int p = atomicAdd(rcnt, 1); rlist[p] = n;
    } else {
        idx_out[n] = (float)bj;
        atomicAdd(&hist[bj], 1);
    }
}

// ---------------- exact fp32 rescore of flagged rows (writes idx/hist too) ------
__global__ __launch_bounds__(256) void vq_rescue(
    const float* __restrict__ z, const float* __restrict__ emb,
    const float* __restrict__ enorm, const int* __restrict__ rcnt,
    const int* __restrict__ rlist, int* __restrict__ idx_ws,
    float* __restrict__ idx_out, int* __restrict__ hist)
{
    __shared__ float zrow[256];
    __shared__ float rs[256];
    __shared__ int   rj[256];
    const int tid = threadIdx.x;
    const int count = *rcnt;

    for (int it = blockIdx.x; it < count; it += gridDim.x) {
        __syncthreads();
        int n = rlist[it];
        zrow[tid] = z[(size_t)(n >> 10) * (CDIM * HW) + (size_t)tid * HW + (n & 1023)];
        __syncthreads();

        float b1 = -3.4e38f; int bj = 0;
#pragma unroll
        for (int jj = 0; jj < 4; ++jj) {
            int j = jj * 256 + tid;
            const float* er = emb + (size_t)j * CDIM;
            float s = 0.f;
#pragma unroll 4
            for (int kc = 0; kc < 256; kc += 4) {
                float4 e = *(const float4*)(er + kc);
                s = fmaf(zrow[kc + 0], e.x, s);
                s = fmaf(zrow[kc + 1], e.y, s);
                s = fmaf(zrow[kc + 2], e.z, s);
                s = fmaf(zrow[kc + 3], e.w, s);
            }
            s -= 0.5f * enorm[j];
            if (s > b1) { b1 = s; bj = j; }
        }
        rs[tid] = b1; rj[tid] = bj;
        __syncthreads();
        for (int step = 128; step >= 1; step >>= 1) {
            if (tid < step) {
                float so = rs[tid + step]; int jo = rj[tid + step];
                if (so > rs[tid] || (so == rs[tid] && jo < rj[tid])) { rs[tid] = so; rj[tid] = jo; }
            }
            __syncthreads();
        }
        if (tid == 0) {
            idx_ws[n] = rj[0];
            idx_out[n] = (float)rj[0];
            atomicAdd(&hist[rj[0]], 1);
        }
    }
}

// ---------------- gather + outputs + loss --------------------------------------
__global__ __launch_bounds__(256) void vq_gather(
    const float* __restrict__ z, const float* __restrict__ emb,
    const int* __restrict__ idx_ws, float* __restrict__ zq,
    float* __restrict__ zq1, double* __restrict__ loss_sum)
{
    __shared__ float es[32 * 129];
    __shared__ int ids[32];
    __shared__ float wred[4];

    const int tid = threadIdx.x, w = tid >> 6, L = tid & 63;
    const int b   = blockIdx.x >> 6;
    const int half = (blockIdx.x >> 5) & 1;
    const int hw0 = (blockIdx.x & 31) << 5;
    const int n0  = (b << 10) + hw0;
    const int c0  = half << 7;

    if (tid < 32) ids[tid] = idx_ws[n0 + tid];
    __syncthreads();

#pragma unroll
    for (int p = 0; p < 4; ++p) {
        int u = p * 256 + tid;
        int r = u >> 5, cq = (u & 31) * 4;
        float4 v = *(const float4*)(emb + (size_t)ids[r] * CDIM + c0 + cq);
        es[r * 129 + cq + 0] = v.x;
        es[r * 129 + cq + 1] = v.y;
        es[r * 129 + cq + 2] = v.z;
        es[r * 129 + cq + 3] = v.w;
    }
    __syncthreads();

    const int row = L & 31, cp = L >> 5;
    const size_t zbase = (size_t)b * (CDIM * HW) + hw0 + row;
    float ls = 0.f;
    for (int rd = 0; rd < 16; ++rd) {
        int cl = rd * 8 + w * 2 + cp;
        size_t off = zbase + (size_t)(c0 + cl) * HW;
        float zv = z[off];
        float e  = es[row * 129 + cl];
        float d  = e - zv;
        zq[off]  = zv + d;     // match ref: zp + (z_q1 - zp)
        zq1[off] = e;
        ls += d * d;
    }

    for (int off = 32; off; off >>= 1) ls += __shfl_down(ls, off, 64);
    if (L == 0) wred[w] = ls;
    __syncthreads();
    if (tid == 0)
        atomicAdd(loss_sum, (double)(wred[0] + wred[1] + wred[2] + wred[3]));
}

// ---------------- finalize: loss scalar + perplexity ---------------------------
__global__ __launch_bounds__(1024) void vq_final(
    const int* __restrict__ hist, const double* __restrict__ loss_sum,
    float* __restrict__ out_loss, float* __restrict__ out_perp)
{
    int tid = threadIdx.x;
    float em = (float)hist[tid] * (1.0f / 32768.0f);
    float term = em * logf(em + 1e-10f);
    for (int off = 32; off; off >>= 1) term += __shfl_down(term, off, 64);
    __shared__ float red[16];
    int lane = tid & 63, wv = tid >> 6;
    if (lane == 0) red[wv] = term;
    __syncthreads();
    if (tid == 0) {
        float s = 0.f;
        for (int i = 0; i < 16; ++i) s += red[i];
        *out_perp = expf(-s);
        *out_loss = (float)(*loss_sum * 1.25 / 8388608.0);
    }
}

extern "C" void kernel_launch(void* const* d_in, const int* in_sizes, int n_in,
                              void* d_out, int out_size, void* d_ws, size_t ws_size,
                              hipStream_t stream) {
    const float* z   = (const float*)d_in[0];
    const float* emb = (const float*)d_in[1];
    float* out = (float*)d_out;
    char*  ws  = (char*)d_ws;

    double* loss_sum    = (double*)(ws + WS_LOSS);
    int*    rcnt        = (int*)(ws + WS_RCNT);
    int*    hist        = (int*)(ws + WS_HIST);
    float*  enorm       = (float*)(ws + WS_ENORM);
    int*    idx_ws      = (int*)(ws + WS_IDX);
    int*    rlist       = (int*)(ws + WS_RLIST);
    float*  s1_ws       = (float*)(ws + WS_S1);
    float*  s2_ws       = (float*)(ws + WS_S2);
    int*    j1_ws       = (int*)(ws + WS_J1);
    unsigned short* ebh = (unsigned short*)(ws + WS_EBH);
    unsigned short* ebl = (unsigned short*)(ws + WS_EBL);
    unsigned short* zbh = (unsigned short*)(ws + WS_ZBH);
    unsigned short* zbl = (unsigned short*)(ws + WS_ZBL);

    hipMemsetAsync(d_ws, 0, 4224, stream);   // loss + rcnt + hist

    vq_prep  <<<528, 256, 0, stream>>>(z, emb, zbh, zbl, ebh, ebl, enorm);
    vq_mfma3 <<<512, 256, 0, stream>>>(zbh, zbl, ebh, ebl, enorm, s1_ws, s2_ws, j1_ws);
    vq_merge <<<128, 256, 0, stream>>>(s1_ws, s2_ws, j1_ws, idx_ws, out + OUT_IDX, hist, rcnt, rlist);
    vq_rescue<<<128, 256, 0, stream>>>(z, emb, enorm, rcnt, rlist, idx_ws, out + OUT_IDX, hist);
    vq_gather<<<2048, 256, 0, stream>>>(z, emb, idx_ws, out + OUT_ZQ, out + OUT_ZQ1, loss_sum);
    vq_final <<<1, 1024, 0, stream>>>(hist, loss_sum, out + OUT_LOSS, out + OUT_PERP);
}

// Round 7
// 275.504 us; speedup vs baseline: 1.8927x; 1.0980x over previous
//
#include <hip/hip_runtime.h>
#include <hip/hip_bf16.h>
#include <math.h>

// Problem constants
#define CDIM 256
#define HW   1024          // 32*32
#define NVEC 32768         // B*H*W
#define NE   1024
#define ZSIZE 8388608      // 32*256*32*32
#define NSPLIT 2           // j-splits (512 codes each)
#define MARGIN 0.05f       // 3-term split-bf16 score error sigma ~1e-4 -> 500 sigma

// Output layout (floats): [loss(1)][z_q(ZSIZE)][perp(1)][idx(NVEC)][z_q1(ZSIZE)]
#define OUT_LOSS 0
#define OUT_ZQ   1
#define OUT_PERP 8388609
#define OUT_IDX  8388610
#define OUT_ZQ1  8421378

// Workspace layout (bytes)
#define WS_LOSS   0
#define WS_RCNT   64
#define WS_HIST   128       // 1024 ints  -> 4224
#define WS_ENORM  4224      // 1024 floats -> 8320
#define WS_IDX    8448      // 32768 ints -> 139520
#define WS_RLIST  139520    // 32768 ints -> 270592
#define WS_S1     270592    // 2*32768 f  -> 532736
#define WS_S2     532736    // -> 794880
#define WS_J1     794880    // -> 1057024
#define WS_EBH    1057024   // 1024*256 bf16 -> 1581312
#define WS_EBL    1581312   // -> 2105600
#define WS_ZBH    2105600   // 32768*256 bf16 -> 18882816
#define WS_ZBL    18882816  // -> 35660032

typedef __attribute__((ext_vector_type(8))) short short8;
typedef __attribute__((ext_vector_type(4))) float f32x4;
typedef __attribute__((ext_vector_type(8))) unsigned short ushort8v;

__device__ __forceinline__ unsigned short bf16_rne(float x) {
    union { float f; unsigned u; } v; v.f = x;
    unsigned r = v.u + 0x7FFFu + ((v.u >> 16) & 1u);
    return (unsigned short)(r >> 16);
}
__device__ __forceinline__ float bf16_to_f(unsigned short h) {
    union { unsigned u; float f; } v; v.u = ((unsigned)h) << 16;
    return v.f;
}
// CK-style block_sync_lds: drains LDS ops + barrier, leaves global loads (vmcnt) in flight.
__device__ __forceinline__ void lds_barrier() {
    asm volatile("s_waitcnt lgkmcnt(0)\n\ts_barrier" ::: "memory");
}

// ---------------- fused prep: z transpose+split (blocks 0..511), emb split+norm (512..527)
__global__ __launch_bounds__(256) void vq_prep(
    const float* __restrict__ z, const float* __restrict__ emb,
    unsigned short* __restrict__ zbh, unsigned short* __restrict__ zbl,
    unsigned short* __restrict__ ebh, unsigned short* __restrict__ ebl,
    float* __restrict__ enorm)
{
    const int tid = threadIdx.x, w = tid >> 6, L = tid & 63;
    if (blockIdx.x < 512) {
        __shared__ unsigned short th[64 * 264];
        __shared__ unsigned short tl[64 * 264];
        const int b = blockIdx.x >> 4, hw0 = (blockIdx.x & 15) << 6;
        const float* zp = z + (size_t)b * (CDIM * HW) + hw0;
        for (int i = 0; i < 16; ++i) {
            int k = (i * 4 + w) * 4;
            float f0 = zp[(size_t)(k + 0) * HW + L];
            float f1 = zp[(size_t)(k + 1) * HW + L];
            float f2 = zp[(size_t)(k + 2) * HW + L];
            float f3 = zp[(size_t)(k + 3) * HW + L];
            ushort4 hi = { bf16_rne(f0), bf16_rne(f1), bf16_rne(f2), bf16_rne(f3) };
            ushort4 lo = { bf16_rne(f0 - bf16_to_f(hi.x)), bf16_rne(f1 - bf16_to_f(hi.y)),
                           bf16_rne(f2 - bf16_to_f(hi.z)), bf16_rne(f3 - bf16_to_f(hi.w)) };
            *(ushort4*)&th[L * 264 + k] = hi;
            *(ushort4*)&tl[L * 264 + k] = lo;
        }
        __syncthreads();
#pragma unroll
        for (int it = 0; it < 8; ++it) {
            int row = it * 8 + (tid >> 5);
            int kc = (tid & 31) * 8;
            size_t o = (size_t)(b * 1024 + hw0 + row) * CDIM + kc;
            *(ushort8v*)(zbh + o) = *(ushort8v*)&th[row * 264 + kc];
            *(ushort8v*)(zbl + o) = *(ushort8v*)&tl[row * 264 + kc];
        }
    } else {
        const int cb = (int)(blockIdx.x - 512) * 64;
        for (int p = 0; p < 16; ++p) {
            int code = cb + p * 4 + w;
            float4 v = *(const float4*)(emb + (size_t)code * CDIM + L * 4);
            float s = v.x * v.x + v.y * v.y + v.z * v.z + v.w * v.w;
            for (int off = 32; off; off >>= 1) s += __shfl_down(s, off, 64);
            if (L == 0) enorm[code] = s;
            ushort4 hi = { bf16_rne(v.x), bf16_rne(v.y), bf16_rne(v.z), bf16_rne(v.w) };
            ushort4 lo = { bf16_rne(v.x - bf16_to_f(hi.x)), bf16_rne(v.y - bf16_to_f(hi.y)),
                           bf16_rne(v.z - bf16_to_f(hi.z)), bf16_rne(v.w - bf16_to_f(hi.w)) };
            *(ushort4*)(ebh + (size_t)code * CDIM + L * 4) = hi;
            *(ushort4*)(ebl + (size_t)code * CDIM + L * 4) = lo;
        }
    }
}

// ---------------- 3-term split-bf16 MFMA GEMM, LDS-staged, j-loop inside ----------
__global__ __launch_bounds__(256, 2) void vq_mfma3(
    const unsigned short* __restrict__ zbh, const unsigned short* __restrict__ zbl,
    const unsigned short* __restrict__ ebh, const unsigned short* __restrict__ ebl,
    const float* __restrict__ enorm,
    float* __restrict__ s1_ws, float* __restrict__ s2_ws, int* __restrict__ j1_ws)
{
    __shared__ short albuf[32768];   // 64KB: AL frags, seg(w,mf,kk)=w*16+mf*8+kk, 512 shorts/seg
    __shared__ short bbuf[8192];     // 16KB: B frags, hi: seg=jf, lo: seg=8+jf

    const int tid = threadIdx.x, w = tid >> 6, L = tid & 63;
    const int l15 = L & 15, q = L >> 4;
    const int r16 = tid & 15, ch = (tid >> 4) & 3;
    const int mtile = blockIdx.x & 255, js = blockIdx.x >> 8;
    const int n0 = mtile << 7;
    const int jsbase = js << 9;

    // stage AL (fragment order)
#pragma unroll
    for (int ro = 0; ro < 16; ++ro) {
        const int seg = ro * 4 + w;
        const int sw2 = seg >> 4, smf = (seg >> 3) & 1, skk = seg & 7;
        short8 v = *(const short8*)(zbl + (size_t)(n0 + sw2 * 32 + smf * 16 + r16) * CDIM + skk * 32 + ch * 8);
        *(short8*)(albuf + seg * 512 + L * 8) = v;
    }
    short8 AH[2][8];
#pragma unroll
    for (int mf = 0; mf < 2; ++mf)
#pragma unroll
        for (int kk = 0; kk < 8; ++kk)
            AH[mf][kk] = *(const short8*)(zbh + (size_t)(n0 + w * 32 + mf * 16 + l15) * CDIM + kk * 32 + q * 8);
    __syncthreads();

    float s1[2][4], s2[2][4]; int j1[2][4];
#pragma unroll
    for (int mf = 0; mf < 2; ++mf)
#pragma unroll
        for (int r = 0; r < 4; ++r) { s1[mf][r] = -3.4e38f; s2[mf][r] = -3.4e38f; j1[mf][r] = 0; }

    for (int j0i = 0; j0i < 4; ++j0i) {
        const int j0 = jsbase + j0i * 128;
        f32x4 acc[2][8] = {};
        short8 st[4];
#pragma unroll
        for (int ro = 0; ro < 4; ++ro) {
            const unsigned short* src = (ro >= 2) ? ebl : ebh;
            const int jf = (ro & 1) * 4 + w;
            st[ro] = *(const short8*)(src + (size_t)(j0 + jf * 16 + r16) * CDIM + ch * 8);
        }
#pragma unroll
        for (int kk = 0; kk < 8; ++kk) {
            lds_barrier();
#pragma unroll
            for (int ro = 0; ro < 4; ++ro)
                *(short8*)(bbuf + (ro * 4 + w) * 512 + L * 8) = st[ro];
            if (kk < 7) {
                const int k0n = (kk + 1) * 32;
#pragma unroll
                for (int ro = 0; ro < 4; ++ro) {
                    const unsigned short* src = (ro >= 2) ? ebl : ebh;
                    const int jf = (ro & 1) * 4 + w;
                    st[ro] = *(const short8*)(src + (size_t)(j0 + jf * 16 + r16) * CDIM + k0n + ch * 8);
                }
            }
            lds_barrier();
            short8 AL0 = *(const short8*)(albuf + (w * 16 + kk) * 512 + L * 8);
            short8 AL1 = *(const short8*)(albuf + (w * 16 + 8 + kk) * 512 + L * 8);
#pragma unroll
            for (int jf = 0; jf < 8; ++jf) {
                short8 Bh = *(const short8*)(bbuf + jf * 512 + L * 8);
                short8 Bl = *(const short8*)(bbuf + (8 + jf) * 512 + L * 8);
                acc[0][jf] = __builtin_amdgcn_mfma_f32_16x16x32_bf16(AH[0][kk], Bh, acc[0][jf], 0, 0, 0);
                acc[1][jf] = __builtin_amdgcn_mfma_f32_16x16x32_bf16(AH[1][kk], Bh, acc[1][jf], 0, 0, 0);
                acc[0][jf] = __builtin_amdgcn_mfma_f32_16x16x32_bf16(AH[0][kk], Bl, acc[0][jf], 0, 0, 0);
                acc[1][jf] = __builtin_amdgcn_mfma_f32_16x16x32_bf16(AH[1][kk], Bl, acc[1][jf], 0, 0, 0);
                acc[0][jf] = __builtin_amdgcn_mfma_f32_16x16x32_bf16(AL0, Bh, acc[0][jf], 0, 0, 0);
                acc[1][jf] = __builtin_amdgcn_mfma_f32_16x16x32_bf16(AL1, Bh, acc[1][jf], 0, 0, 0);
            }
        }
#pragma unroll
        for (int jf = 0; jf < 8; ++jf) {
            const int j = j0 + jf * 16 + l15;
            const float hn = 0.5f * enorm[j];
#pragma unroll
            for (int mf = 0; mf < 2; ++mf)
#pragma unroll
                for (int r = 0; r < 4; ++r) {
                    float s = acc[mf][jf][r] - hn;
                    if (s > s1[mf][r]) { s2[mf][r] = s1[mf][r]; s1[mf][r] = s; j1[mf][r] = j; }
                    else if (s > s2[mf][r]) s2[mf][r] = s;
                }
        }
    }

#pragma unroll
    for (int mf = 0; mf < 2; ++mf)
#pragma unroll
        for (int r = 0; r < 4; ++r) {
            float a1 = s1[mf][r], a2 = s2[mf][r]; int aj = j1[mf][r];
            for (int m = 1; m < 16; m <<= 1) {
                float o1 = __shfl_xor(a1, m, 64);
                float o2 = __shfl_xor(a2, m, 64);
                int   oj = __shfl_xor(aj, m, 64);
                if (o1 > a1 || (o1 == a1 && oj < aj)) { a2 = fmaxf(a1, o2); a1 = o1; aj = oj; }
                else a2 = fmaxf(a2, o1);
            }
            if (l15 == 0) {
                int o = js * NVEC + n0 + w * 32 + mf * 16 + q * 4 + r;
                s1_ws[o] = a1; s2_ws[o] = a2; j1_ws[o] = aj;
            }
        }
}

// ---------------- merge 2 splits; hist+idx_out for confident rows; flag rest ----
__global__ __launch_bounds__(256) void vq_merge(
    const float* __restrict__ s1_ws, const float* __restrict__ s2_ws,
    const int* __restrict__ j1_ws, int* __restrict__ idx_ws,
    float* __restrict__ idx_out, int* __restrict__ hist,
    int* __restrict__ rcnt, int* __restrict__ rlist)
{
    int n = blockIdx.x * 256 + threadIdx.x;
    float b1 = -3.4e38f, b2 = -3.4e38f; int bj = 0;
#pragma unroll
    for (int s = 0; s < NSPLIT; ++s) {
        float a1 = s1_ws[s * NVEC + n], a2 = s2_ws[s * NVEC + n];
        int aj = j1_ws[s * NVEC + n];
        if (a1 > b1 || (a1 == b1 && aj < bj)) { b2 = fmaxf(b1, a2); b1 = a1; bj = aj; }
        else b2 = fmaxf(b2, a1);
    }
    idx_ws[n] = bj;
    if (b1 - b2 < MARGIN) {
        int p = atomicAdd(rcnt, 1); rlist[p] = n;
    } else {
        idx_out[n] = (float)bj;
        atomicAdd(&hist[bj], 1);
    }
}

// ---------------- exact fp32 rescore of flagged rows ---------------------------
// One row per block; each thread owns 4 INTERLEAVED dot products (j = tid + q*256)
// -> 4 independent load/FMA chains per thread, kc-loop outermost for ILP.
__global__ __launch_bounds__(256) void vq_rescue(
    const float* __restrict__ z, const float* __restrict__ emb,
    const float* __restrict__ enorm, const int* __restrict__ rcnt,
    const int* __restrict__ rlist, int* __restrict__ idx_ws,
    float* __restrict__ idx_out, int* __restrict__ hist)
{
    __shared__ __align__(16) float zrow[256];
    __shared__ float rs[256];
    __shared__ int   rj[256];
    const int tid = threadIdx.x;
    const int count = *rcnt;

    for (int it = blockIdx.x; it < count; it += gridDim.x) {
        __syncthreads();
        int n = rlist[it];
        zrow[tid] = z[(size_t)(n >> 10) * (CDIM * HW) + (size_t)tid * HW + (n & 1023)];
        __syncthreads();

        const float* er0 = emb + (size_t)(tid      ) * CDIM;
        const float* er1 = emb + (size_t)(tid + 256) * CDIM;
        const float* er2 = emb + (size_t)(tid + 512) * CDIM;
        const float* er3 = emb + (size_t)(tid + 768) * CDIM;
        float s0 = 0.f, sA = 0.f, sB = 0.f, sC = 0.f;
#pragma unroll 4
        for (int kc = 0; kc < 256; kc += 4) {
            float4 zv = *(const float4*)&zrow[kc];       // LDS broadcast (free)
            float4 e0 = *(const float4*)(er0 + kc);      // 4 independent chains
            float4 e1 = *(const float4*)(er1 + kc);
            float4 e2 = *(const float4*)(er2 + kc);
            float4 e3 = *(const float4*)(er3 + kc);
            s0 = fmaf(zv.x, e0.x, s0); s0 = fmaf(zv.y, e0.y, s0);
            s0 = fmaf(zv.z, e0.z, s0); s0 = fmaf(zv.w, e0.w, s0);
            sA = fmaf(zv.x, e1.x, sA); sA = fmaf(zv.y, e1.y, sA);
            sA = fmaf(zv.z, e1.z, sA); sA = fmaf(zv.w, e1.w, sA);
            sB = fmaf(zv.x, e2.x, sB); sB = fmaf(zv.y, e2.y, sB);
            sB = fmaf(zv.z, e2.z, sB); sB = fmaf(zv.w, e2.w, sB);
            sC = fmaf(zv.x, e3.x, sC); sC = fmaf(zv.y, e3.y, sC);
            sC = fmaf(zv.z, e3.z, sC); sC = fmaf(zv.w, e3.w, sC);
        }
        s0 -= 0.5f * enorm[tid];
        sA -= 0.5f * enorm[tid + 256];
        sB -= 0.5f * enorm[tid + 512];
        sC -= 0.5f * enorm[tid + 768];
        // per-thread fold, j ascending (strict > keeps smallest j on ties)
        float b1 = s0; int bj = tid;
        if (sA > b1) { b1 = sA; bj = tid + 256; }
        if (sB > b1) { b1 = sB; bj = tid + 512; }
        if (sC > b1) { b1 = sC; bj = tid + 768; }
        rs[tid] = b1; rj[tid] = bj;
        __syncthreads();
        for (int step = 128; step >= 1; step >>= 1) {
            if (tid < step) {
                float so = rs[tid + step]; int jo = rj[tid + step];
                if (so > rs[tid] || (so == rs[tid] && jo < rj[tid])) { rs[tid] = so; rj[tid] = jo; }
            }
            __syncthreads();
        }
        if (tid == 0) {
            idx_ws[n] = rj[0];
            idx_out[n] = (float)rj[0];
            atomicAdd(&hist[rj[0]], 1);
        }
    }
}

// ---------------- gather + outputs + loss --------------------------------------
__global__ __launch_bounds__(256) void vq_gather(
    const float* __restrict__ z, const float* __restrict__ emb,
    const int* __restrict__ idx_ws, float* __restrict__ zq,
    float* __restrict__ zq1, double* __restrict__ loss_sum)
{
    __shared__ float es[32 * 129];
    __shared__ int ids[32];
    __shared__ float wred[4];

    const int tid = threadIdx.x, w = tid >> 6, L = tid & 63;
    const int b   = blockIdx.x >> 6;
    const int half = (blockIdx.x >> 5) & 1;
    const int hw0 = (blockIdx.x & 31) << 5;
    const int n0  = (b << 10) + hw0;
    const int c0  = half << 7;

    if (tid < 32) ids[tid] = idx_ws[n0 + tid];
    __syncthreads();

#pragma unroll
    for (int p = 0; p < 4; ++p) {
        int u = p * 256 + tid;
        int r = u >> 5, cq = (u & 31) * 4;
        float4 v = *(const float4*)(emb + (size_t)ids[r] * CDIM + c0 + cq);
        es[r * 129 + cq + 0] = v.x;
        es[r * 129 + cq + 1] = v.y;
        es[r * 129 + cq + 2] = v.z;
        es[r * 129 + cq + 3] = v.w;
    }
    __syncthreads();

    const int row = L & 31, cp = L >> 5;
    const size_t zbase = (size_t)b * (CDIM * HW) + hw0 + row;
    float ls = 0.f;
    for (int rd = 0; rd < 16; ++rd) {
        int cl = rd * 8 + w * 2 + cp;
        size_t off = zbase + (size_t)(c0 + cl) * HW;
        float zv = z[off];
        float e  = es[row * 129 + cl];
        float d  = e - zv;
        zq[off]  = zv + d;     // match ref: zp + (z_q1 - zp)
        zq1[off] = e;
        ls += d * d;
    }

    for (int off = 32; off; off >>= 1) ls += __shfl_down(ls, off, 64);
    if (L == 0) wred[w] = ls;
    __syncthreads();
    if (tid == 0)
        atomicAdd(loss_sum, (double)(wred[0] + wred[1] + wred[2] + wred[3]));
}

// ---------------- finalize: loss scalar + perplexity ---------------------------
__global__ __launch_bounds__(1024) void vq_final(
    const int* __restrict__ hist, const double* __restrict__ loss_sum,
    float* __restrict__ out_loss, float* __restrict__ out_perp)
{
    int tid = threadIdx.x;
    float em = (float)hist[tid] * (1.0f / 32768.0f);
    float term = em * logf(em + 1e-10f);
    for (int off = 32; off; off >>= 1) term += __shfl_down(term, off, 64);
    __shared__ float red[16];
    int lane = tid & 63, wv = tid >> 6;
    if (lane == 0) red[wv] = term;
    __syncthreads();
    if (tid == 0) {
        float s = 0.f;
        for (int i = 0; i < 16; ++i) s += red[i];
        *out_perp = expf(-s);
        *out_loss = (float)(*loss_sum * 1.25 / 8388608.0);
    }
}

extern "C" void kernel_launch(void* const* d_in, const int* in_sizes, int n_in,
                              void* d_out, int out_size, void* d_ws, size_t ws_size,
                              hipStream_t stream) {
    const float* z   = (const float*)d_in[0];
    const float* emb = (const float*)d_in[1];
    float* out = (float*)d_out;
    char*  ws  = (char*)d_ws;

    double* loss_sum    = (double*)(ws + WS_LOSS);
    int*    rcnt        = (int*)(ws + WS_RCNT);
    int*    hist        = (int*)(ws + WS_HIST);
    float*  enorm       = (float*)(ws + WS_ENORM);
    int*    idx_ws      = (int*)(ws + WS_IDX);
    int*    rlist       = (int*)(ws + WS_RLIST);
    float*  s1_ws       = (float*)(ws + WS_S1);
    float*  s2_ws       = (float*)(ws + WS_S2);
    int*    j1_ws       = (int*)(ws + WS_J1);
    unsigned short* ebh = (unsigned short*)(ws + WS_EBH);
    unsigned short* ebl = (unsigned short*)(ws + WS_EBL);
    unsigned short* zbh = (unsigned short*)(ws + WS_ZBH);
    unsigned short* zbl = (unsigned short*)(ws + WS_ZBL);

    hipMemsetAsync(d_ws, 0, 4224, stream);   // loss + rcnt + hist

    vq_prep  <<<528, 256, 0, stream>>>(z, emb, zbh, zbl, ebh, ebl, enorm);
    vq_mfma3 <<<512, 256, 0, stream>>>(zbh, zbl, ebh, ebl, enorm, s1_ws, s2_ws, j1_ws);
    vq_merge <<<128, 256, 0, stream>>>(s1_ws, s2_ws, j1_ws, idx_ws, out + OUT_IDX, hist, rcnt, rlist);
    vq_rescue<<<512, 256, 0, stream>>>(z, emb, enorm, rcnt, rlist, idx_ws, out + OUT_IDX, hist);
    vq_gather<<<2048, 256, 0, stream>>>(z, emb, idx_ws, out + OUT_ZQ, out + OUT_ZQ1, loss_sum);
    vq_final <<<1, 1024, 0, stream>>>(hist, loss_sum, out + OUT_LOSS, out + OUT_PERP);
}